// Round 1
// baseline (49128.381 us; speedup 1.0000x reference)
//
#include <hip/hip_runtime.h>
#include <hip/hip_bf16.h>
#include <math.h>

#define DIM 256
#define NROWS 8192
#define QBLK 32
#define KBLK 64
#define QSTR 260   // padded LDS stride for Q tile (floats)
#define KSTR 260   // padded LDS stride for K/V tile (floats)
#define SSTR 68    // padded LDS stride for S tile (floats)

// ---------------------------------------------------------------------------
// Kernel 1: QKV projection. Y = X @ W^T  (NT gemm: dot along contiguous k)
// grid (NROWS/64, DIM/64, 3), block 256. Classic 64x64 tile, 4x4 per thread.
// ---------------------------------------------------------------------------
__global__ __launch_bounds__(256) void qkv_proj_kernel(
    const float* __restrict__ X, const float* __restrict__ Wq,
    const float* __restrict__ Wk, const float* __restrict__ Wv,
    float* __restrict__ Qo, float* __restrict__ Ko, float* __restrict__ Vo)
{
    const float* W = (blockIdx.z == 0) ? Wq : (blockIdx.z == 1) ? Wk : Wv;
    float* Y       = (blockIdx.z == 0) ? Qo : (blockIdx.z == 1) ? Ko : Vo;

    const int row0 = blockIdx.x * 64;
    const int col0 = blockIdx.y * 64;

    __shared__ float Xs[16][65];   // [kk][row]
    __shared__ float Ws[16][65];   // [kk][col]

    const int t  = threadIdx.x;
    const int tx = t & 15;         // col group
    const int ty = t >> 4;         // row group

    float acc[4][4] = {};

    for (int k0 = 0; k0 < DIM; k0 += 16) {
        #pragma unroll
        for (int i = 0; i < 4; ++i) {
            int idx = t + i * 256;          // 0..1023
            int r  = idx >> 4;              // 0..63
            int kk = idx & 15;
            Xs[kk][r] = X[(size_t)(row0 + r) * DIM + k0 + kk];
            Ws[kk][r] = W[(size_t)(col0 + r) * DIM + k0 + kk];
        }
        __syncthreads();
        #pragma unroll
        for (int kk = 0; kk < 16; ++kk) {
            float a[4], b[4];
            #pragma unroll
            for (int i = 0; i < 4; ++i) a[i] = Xs[kk][ty * 4 + i];
            #pragma unroll
            for (int j = 0; j < 4; ++j) b[j] = Ws[kk][tx * 4 + j];
            #pragma unroll
            for (int i = 0; i < 4; ++i)
                #pragma unroll
                for (int j = 0; j < 4; ++j)
                    acc[i][j] += a[i] * b[j];
        }
        __syncthreads();
    }

    #pragma unroll
    for (int i = 0; i < 4; ++i)
        #pragma unroll
        for (int j = 0; j < 4; ++j)
            Y[(size_t)(row0 + ty * 4 + i) * DIM + col0 + tx * 4 + j] = acc[i][j];
}

// ---------------------------------------------------------------------------
// Kernel 2: fp32 flash attention.
// grid NROWS/QBLK = 256 blocks, 256 threads.
// Per block: 32 query rows. Iterate keys in tiles of 64.
//   S-phase mapping:  sk = t&15 (keys sk, sk+16, sk+32, sk+48), sy = t>>4 (q pair)
//   PV-phase mapping: tx = t&15 (d group of 16), ty = t>>4 (q pair)
// ---------------------------------------------------------------------------
__global__ __launch_bounds__(256) void attn_kernel(
    const float* __restrict__ Q, const float* __restrict__ K,
    const float* __restrict__ V, float* __restrict__ O)
{
    __shared__ float Qs[QBLK][QSTR];
    __shared__ float KVs[KBLK][KSTR];     // K tile, then reused for V tile
    __shared__ float Ss[QBLK][SSTR];
    __shared__ float m_s[QBLK], l_s[QBLK], scale_s[QBLK];

    const int t  = threadIdx.x;
    const int q0 = blockIdx.x * QBLK;

    // --- load Q tile (32 x 256) ---
    #pragma unroll
    for (int i = 0; i < 8; ++i) {
        int idx = t + i * 256;            // float4 index, 0..2047
        int r  = idx >> 6;                // 0..31
        int c4 = idx & 63;
        *(float4*)&Qs[r][c4 * 4] = *(const float4*)&Q[(size_t)(q0 + r) * DIM + c4 * 4];
    }
    if (t < QBLK) { m_s[t] = -INFINITY; l_s[t] = 0.0f; }

    const int sk = t & 15;
    const int sy = t >> 4;
    const int tx = t & 15;
    const int ty = t >> 4;

    float O_acc[2][16] = {};              // [q pair][d within 16-group]
    const float inv_sqrt_d = 0.0625f;     // 1/sqrt(256)

    for (int kt = 0; kt < NROWS; kt += KBLK) {
        __syncthreads();                  // prev PV done reading KVs (and Q load done, 1st iter)

        // --- load K tile (64 x 256) ---
        #pragma unroll
        for (int i = 0; i < 16; ++i) {
            int idx = t + i * 256;        // 0..4095 float4
            int r  = idx >> 6;            // 0..63
            int c4 = idx & 63;
            *(float4*)&KVs[r][c4 * 4] = *(const float4*)&K[(size_t)(kt + r) * DIM + c4 * 4];
        }
        __syncthreads();

        // --- S = Q K^T (each thread: 2 q rows x 4 keys) ---
        float s_acc[2][4] = {};
        #pragma unroll 4
        for (int kk = 0; kk < DIM; kk += 4) {
            float4 qa = *(float4*)&Qs[sy * 2 + 0][kk];
            float4 qb = *(float4*)&Qs[sy * 2 + 1][kk];
            #pragma unroll
            for (int j = 0; j < 4; ++j) {
                float4 kv = *(float4*)&KVs[sk + 16 * j][kk];
                s_acc[0][j] += qa.x * kv.x + qa.y * kv.y + qa.z * kv.z + qa.w * kv.w;
                s_acc[1][j] += qb.x * kv.x + qb.y * kv.y + qb.z * kv.z + qb.w * kv.w;
            }
        }
        #pragma unroll
        for (int j = 0; j < 4; ++j) {
            Ss[sy * 2 + 0][sk + 16 * j] = s_acc[0][j] * inv_sqrt_d;
            Ss[sy * 2 + 1][sk + 16 * j] = s_acc[1][j] * inv_sqrt_d;
        }
        __syncthreads();

        // --- online softmax over this tile (8 threads per row) ---
        {
            const int row   = t >> 3;     // 0..31
            const int lane8 = t & 7;      // position within row group
            float mx = -INFINITY;
            #pragma unroll
            for (int j = 0; j < 8; ++j) mx = fmaxf(mx, Ss[row][lane8 * 8 + j]);
            #pragma unroll
            for (int off = 1; off < 8; off <<= 1) mx = fmaxf(mx, __shfl_xor(mx, off));

            float m_old = m_s[row];
            float m_new = fmaxf(m_old, mx);

            float sum = 0.0f;
            #pragma unroll
            for (int j = 0; j < 8; ++j) {
                float p = __expf(Ss[row][lane8 * 8 + j] - m_new);
                Ss[row][lane8 * 8 + j] = p;
                sum += p;
            }
            #pragma unroll
            for (int off = 1; off < 8; off <<= 1) sum += __shfl_xor(sum, off);

            if (lane8 == 0) {
                float corr = __expf(m_old - m_new);
                scale_s[row] = corr;
                l_s[row] = l_s[row] * corr + sum;
                m_s[row] = m_new;
            }
        }
        __syncthreads();

        // --- load V tile into KVs (K already consumed) ---
        #pragma unroll
        for (int i = 0; i < 16; ++i) {
            int idx = t + i * 256;
            int r  = idx >> 6;
            int c4 = idx & 63;
            *(float4*)&KVs[r][c4 * 4] = *(const float4*)&V[(size_t)(kt + r) * DIM + c4 * 4];
        }
        __syncthreads();

        // --- rescale O, then O += P V ---
        {
            float c0 = scale_s[ty * 2 + 0];
            float c1 = scale_s[ty * 2 + 1];
            #pragma unroll
            for (int d = 0; d < 16; ++d) { O_acc[0][d] *= c0; O_acc[1][d] *= c1; }

            for (int k = 0; k < KBLK; ++k) {
                float p0 = Ss[ty * 2 + 0][k];
                float p1 = Ss[ty * 2 + 1][k];
                #pragma unroll
                for (int c = 0; c < 4; ++c) {
                    int dq = (c + (tx >> 1)) & 3;          // bank-spread issue order
                    float4 v = *(float4*)&KVs[k][tx * 16 + dq * 4];
                    O_acc[0][dq * 4 + 0] += p0 * v.x;
                    O_acc[0][dq * 4 + 1] += p0 * v.y;
                    O_acc[0][dq * 4 + 2] += p0 * v.z;
                    O_acc[0][dq * 4 + 3] += p0 * v.w;
                    O_acc[1][dq * 4 + 0] += p1 * v.x;
                    O_acc[1][dq * 4 + 1] += p1 * v.y;
                    O_acc[1][dq * 4 + 2] += p1 * v.z;
                    O_acc[1][dq * 4 + 3] += p1 * v.w;
                }
            }
        }
    }

    // --- epilogue: O / l ---
    {
        float r0 = 1.0f / l_s[ty * 2 + 0];
        float r1 = 1.0f / l_s[ty * 2 + 1];
        #pragma unroll
        for (int c = 0; c < 4; ++c) {
            float4 o0, o1;
            o0.x = O_acc[0][c * 4 + 0] * r0; o0.y = O_acc[0][c * 4 + 1] * r0;
            o0.z = O_acc[0][c * 4 + 2] * r0; o0.w = O_acc[0][c * 4 + 3] * r0;
            o1.x = O_acc[1][c * 4 + 0] * r1; o1.y = O_acc[1][c * 4 + 1] * r1;
            o1.z = O_acc[1][c * 4 + 2] * r1; o1.w = O_acc[1][c * 4 + 3] * r1;
            *(float4*)&O[(size_t)(q0 + ty * 2 + 0) * DIM + tx * 16 + c * 4] = o0;
            *(float4*)&O[(size_t)(q0 + ty * 2 + 1) * DIM + tx * 16 + c * 4] = o1;
        }
    }
}

extern "C" void kernel_launch(void* const* d_in, const int* in_sizes, int n_in,
                              void* d_out, int out_size, void* d_ws, size_t ws_size,
                              hipStream_t stream) {
    const float* X  = (const float*)d_in[0];
    const float* Wq = (const float*)d_in[1];
    const float* Wk = (const float*)d_in[2];
    const float* Wv = (const float*)d_in[3];
    float* out = (float*)d_out;

    float* ws = (float*)d_ws;
    float* Q  = ws;
    float* K  = ws + (size_t)NROWS * DIM;
    float* V  = ws + 2 * (size_t)NROWS * DIM;

    qkv_proj_kernel<<<dim3(NROWS / 64, DIM / 64, 3), 256, 0, stream>>>(X, Wq, Wk, Wv, Q, K, V);
    attn_kernel<<<dim3(NROWS / QBLK), 256, 0, stream>>>(Q, K, V, out);
}

// Round 2
// 329.845 us; speedup vs baseline: 148.9438x; 148.9438x over previous
//
#include <hip/hip_runtime.h>
#include <math.h>

#define N 8192
#define D 256
#define QBLK 64
#define KBLK 64
#define NT (N / KBLK)

typedef float f32x4 __attribute__((ext_vector_type(4)));
typedef short bf16x8 __attribute__((ext_vector_type(8)));

#define MFMA(a, b, c) __builtin_amdgcn_mfma_f32_16x16x32_bf16((a), (b), (c), 0, 0, 0)

__device__ __forceinline__ unsigned short f2b(float f) {
    unsigned u = __builtin_bit_cast(unsigned, f);
    u = u + 0x7fffu + ((u >> 16) & 1u);            // RNE
    return (unsigned short)(u >> 16);
}
__device__ __forceinline__ unsigned pk2(float a, float b) {
    return (unsigned)f2b(a) | ((unsigned)f2b(b) << 16);
}

// ---------------------------------------------------------------------------
// QKV projection via MFMA. Y = X @ W^T (NT gemm). Q,K row-major bf16; V
// stored TRANSPOSED (Vt[d][key], key contiguous) for the attention PV phase.
// grid (N/64, D/64, 3), block 256 (4 waves x 16 rows).
// ---------------------------------------------------------------------------
__global__ __launch_bounds__(256) void proj_mfma(
    const float* __restrict__ X, const float* __restrict__ Wq,
    const float* __restrict__ Wk, const float* __restrict__ Wv,
    unsigned short* __restrict__ Qb, unsigned short* __restrict__ Kb,
    unsigned short* __restrict__ Vt)
{
    __shared__ char Wl[32768];                     // 64 out-cols x 256 k, bf16, XOR-swizzled
    const int z = blockIdx.z;
    const float* W = (z == 0) ? Wq : (z == 1) ? Wk : Wv;
    const int r0 = blockIdx.x * 64;
    const int c0 = blockIdx.y * 64;
    const int t = threadIdx.x, w = t >> 6, l = t & 63;
    const int lo = l & 15, hi = l >> 4;

    // stage W tile -> bf16 LDS, swizzle byte ^= ((col&7)<<4)
    #pragma unroll
    for (int i = 0; i < 16; ++i) {
        int e4 = t + i * 256;
        int col = e4 >> 6, kk4 = e4 & 63;
        float4 f = *(const float4*)&W[(size_t)(c0 + col) * D + kk4 * 4];
        unsigned long long v = (unsigned long long)pk2(f.x, f.y)
                             | ((unsigned long long)pk2(f.z, f.w) << 32);
        *(unsigned long long*)(Wl + col * 512 + ((kk4 * 8) ^ ((col & 7) << 4))) = v;
    }
    __syncthreads();

    // X fragments (A-operand): row = lo, k = 32*ks + 8*hi + j
    bf16x8 xf[8];
    {
        const float* xr = X + (size_t)(r0 + w * 16 + lo) * D;
        #pragma unroll
        for (int ks = 0; ks < 8; ++ks) {
            float4 a = *(const float4*)(xr + ks * 32 + hi * 8);
            float4 b = *(const float4*)(xr + ks * 32 + hi * 8 + 4);
            bf16x8 v;
            v[0] = (short)f2b(a.x); v[1] = (short)f2b(a.y);
            v[2] = (short)f2b(a.z); v[3] = (short)f2b(a.w);
            v[4] = (short)f2b(b.x); v[5] = (short)f2b(b.y);
            v[6] = (short)f2b(b.z); v[7] = (short)f2b(b.w);
            xf[ks] = v;
        }
    }

    f32x4 acc[4];
    #pragma unroll
    for (int nc = 0; nc < 4; ++nc) acc[nc] = (f32x4){0.f, 0.f, 0.f, 0.f};
    #pragma unroll
    for (int ks = 0; ks < 8; ++ks) {
        #pragma unroll
        for (int nc = 0; nc < 4; ++nc) {
            int col = nc * 16 + lo;
            bf16x8 wf = *(const bf16x8*)(Wl + col * 512 +
                                         ((ks * 64 + hi * 16) ^ ((col & 7) << 4)));
            acc[nc] = MFMA(xf[ks], wf, acc[nc]);
        }
    }

    if (z < 2) {
        unsigned short* Y = z ? Kb : Qb;
        #pragma unroll
        for (int nc = 0; nc < 4; ++nc)
            #pragma unroll
            for (int r = 0; r < 4; ++r)
                Y[(size_t)(r0 + w * 16 + hi * 4 + r) * D + c0 + nc * 16 + lo] = f2b(acc[nc][r]);
    } else {
        // transposed store: Vt[d][key], 4 consecutive keys -> 8B store
        #pragma unroll
        for (int nc = 0; nc < 4; ++nc) {
            unsigned long long v = (unsigned long long)pk2(acc[nc][0], acc[nc][1])
                                 | ((unsigned long long)pk2(acc[nc][2], acc[nc][3]) << 32);
            *(unsigned long long*)&Vt[(size_t)(c0 + nc * 16 + lo) * N + r0 + w * 16 + hi * 4] = v;
        }
    }
}

// ---------------------------------------------------------------------------
// bf16 MFMA flash attention. grid N/64 blocks, 4 waves x 16 q-rows.
// S^T = mfma(K, Q) so softmax is lane-local. K tiles [64][256] and Vt tiles
// [256][64] double-buffered in LDS via global_load_lds w=16 with pre-swizzled
// source (XOR ((row&7)<<4)). P re-fragmented through padded per-wave LDS.
// LDS: K 2x32KB @0, Vt 2x32KB @65536, P 4x2304B @131072  -> 140288 B.
// ---------------------------------------------------------------------------
__global__ __launch_bounds__(256) void attn_mfma(
    const unsigned short* __restrict__ Qb,
    const unsigned short* __restrict__ Kb,
    const unsigned short* __restrict__ Vt,
    float* __restrict__ O)
{
    extern __shared__ char smem[];
    const int t = threadIdx.x;
    const int w = t >> 6;
    const int l = t & 63;
    const int lo = l & 15;
    const int hi = l >> 4;
    const int q0 = blockIdx.x * QBLK;

    char* Pw = smem + 131072 + w * 2304;           // [16 q][72 keys] bf16 (pad 64->72)

    // resident Q fragments (B-operand): col = lo, k = 32*ks + 8*hi + j
    bf16x8 qf[8];
    {
        const unsigned short* qrow = Qb + (size_t)(q0 + w * 16 + lo) * D;
        #pragma unroll
        for (int ks = 0; ks < 8; ++ks)
            qf[ks] = *(const bf16x8*)(qrow + ks * 32 + hi * 8);
    }

    // prologue: stage tile 0 into buffer 0
    #pragma unroll
    for (int i = 0; i < 8; ++i) {
        int c = w * 8 + i;
        int dst = c * 64 + l;                      // 16B units
        {
            int key = dst >> 5, xc = dst & 31;
            const unsigned short* gp = Kb + (size_t)key * D + (xc ^ (key & 7)) * 8;
            __builtin_amdgcn_global_load_lds(
                (const __attribute__((address_space(1))) void*)gp,
                (__attribute__((address_space(3))) void*)(smem + c * 1024), 16, 0, 0);
        }
        {
            int dd = dst >> 3, xc = dst & 7;
            const unsigned short* gp = Vt + (size_t)dd * N + (xc ^ (dd & 7)) * 8;
            __builtin_amdgcn_global_load_lds(
                (const __attribute__((address_space(1))) void*)gp,
                (__attribute__((address_space(3))) void*)(smem + 65536 + c * 1024), 16, 0, 0);
        }
    }

    f32x4 Oacc[16];
    #pragma unroll
    for (int i = 0; i < 16; ++i) Oacc[i] = (f32x4){0.f, 0.f, 0.f, 0.f};
    float m_run = -INFINITY, l_run = 0.f;
    const float scale = 0.0625f;                   // 1/sqrt(256)

    __syncthreads();                               // drains vmcnt -> tile 0 ready

    for (int tt = 0; tt < NT; ++tt) {
        const int cur = tt & 1;

        // issue next-tile staging into the other buffer (in flight during compute)
        if (tt + 1 < NT) {
            const int ktn = (tt + 1) * KBLK;
            #pragma unroll
            for (int i = 0; i < 8; ++i) {
                int c = w * 8 + i;
                int dst = c * 64 + l;
                {
                    int key = dst >> 5, xc = dst & 31;
                    const unsigned short* gp = Kb + (size_t)(ktn + key) * D + (xc ^ (key & 7)) * 8;
                    __builtin_amdgcn_global_load_lds(
                        (const __attribute__((address_space(1))) void*)gp,
                        (__attribute__((address_space(3))) void*)(smem + (cur ^ 1) * 32768 + c * 1024),
                        16, 0, 0);
                }
                {
                    int dd = dst >> 3, xc = dst & 7;
                    const unsigned short* gp = Vt + (size_t)dd * N + ktn + (xc ^ (dd & 7)) * 8;
                    __builtin_amdgcn_global_load_lds(
                        (const __attribute__((address_space(1))) void*)gp,
                        (__attribute__((address_space(3))) void*)(smem + 65536 + (cur ^ 1) * 32768 + c * 1024),
                        16, 0, 0);
                }
            }
        }

        const char* Kl = smem + cur * 32768;
        const char* Vl = smem + 65536 + cur * 32768;

        // ---- S^T = K . Q^T : D[key][q], lane: q = lo, keys = 16nc + 4hi + r
        f32x4 sacc[4];
        #pragma unroll
        for (int nc = 0; nc < 4; ++nc) sacc[nc] = (f32x4){0.f, 0.f, 0.f, 0.f};
        #pragma unroll
        for (int ks = 0; ks < 8; ++ks) {
            #pragma unroll
            for (int nc = 0; nc < 4; ++nc) {
                int key = nc * 16 + lo;
                bf16x8 kf = *(const bf16x8*)(Kl + key * 512 +
                                             ((ks * 64 + hi * 16) ^ ((key & 7) << 4)));
                sacc[nc] = MFMA(kf, qf[ks], sacc[nc]);
            }
        }

        // ---- online softmax: 16 in-lane values + shfl_xor(16,32)
        float mx = -INFINITY;
        #pragma unroll
        for (int nc = 0; nc < 4; ++nc)
            #pragma unroll
            for (int r = 0; r < 4; ++r) mx = fmaxf(mx, sacc[nc][r]);
        mx *= scale;
        mx = fmaxf(mx, __shfl_xor(mx, 16));
        mx = fmaxf(mx, __shfl_xor(mx, 32));
        float m_new = fmaxf(m_run, mx);
        float corr = __expf(m_run - m_new);
        float p[16];
        float tsum = 0.f;
        #pragma unroll
        for (int nc = 0; nc < 4; ++nc)
            #pragma unroll
            for (int r = 0; r < 4; ++r) {
                float pv = __expf(sacc[nc][r] * scale - m_new);
                p[nc * 4 + r] = pv;
                tsum += pv;
            }
        tsum += __shfl_xor(tsum, 16);
        tsum += __shfl_xor(tsum, 32);
        l_run = l_run * corr + tsum;
        m_run = m_new;

        // ---- write P (bf16) to per-wave padded LDS: row q=lo, stride 144B
        #pragma unroll
        for (int nc = 0; nc < 4; ++nc) {
            *(unsigned*)(Pw + lo * 144 + (nc * 16 + hi * 4) * 2)     = pk2(p[nc * 4 + 0], p[nc * 4 + 1]);
            *(unsigned*)(Pw + lo * 144 + (nc * 16 + hi * 4 + 2) * 2) = pk2(p[nc * 4 + 2], p[nc * 4 + 3]);
        }
        __threadfence_block();                     // order P write -> P read (same wave)

        // ---- rescale O by corr (per O-row q = 4hi + r)
        float cr[4];
        #pragma unroll
        for (int r = 0; r < 4; ++r) cr[r] = __shfl(corr, hi * 4 + r);
        #pragma unroll
        for (int nc = 0; nc < 16; ++nc) {
            Oacc[nc][0] *= cr[0]; Oacc[nc][1] *= cr[1];
            Oacc[nc][2] *= cr[2]; Oacc[nc][3] *= cr[3];
        }

        // ---- PV: A = P fragments, B = Vt fragments
        bf16x8 pa0 = *(const bf16x8*)(Pw + lo * 144 + hi * 16);
        bf16x8 pa1 = *(const bf16x8*)(Pw + lo * 144 + 64 + hi * 16);
        #pragma unroll
        for (int nc = 0; nc < 16; ++nc) {
            int dd = nc * 16 + lo;
            bf16x8 v0 = *(const bf16x8*)(Vl + dd * 128 + ((hi * 16) ^ ((dd & 7) << 4)));
            bf16x8 v1 = *(const bf16x8*)(Vl + dd * 128 + ((64 + hi * 16) ^ ((dd & 7) << 4)));
            Oacc[nc] = MFMA(pa0, v0, Oacc[nc]);
            Oacc[nc] = MFMA(pa1, v1, Oacc[nc]);
        }

        __syncthreads();                           // next tile landed; all waves done with cur
    }

    // ---- epilogue: O / l
    float rinv = 1.0f / l_run;
    float rv[4];
    #pragma unroll
    for (int r = 0; r < 4; ++r) rv[r] = __shfl(rinv, hi * 4 + r);
    const int qrow = q0 + w * 16 + hi * 4;
    #pragma unroll
    for (int nc = 0; nc < 16; ++nc) {
        #pragma unroll
        for (int r = 0; r < 4; ++r)
            O[(size_t)(qrow + r) * D + nc * 16 + lo] = Oacc[nc][r] * rv[r];
    }
}

extern "C" void kernel_launch(void* const* d_in, const int* in_sizes, int n_in,
                              void* d_out, int out_size, void* d_ws, size_t ws_size,
                              hipStream_t stream) {
    const float* X  = (const float*)d_in[0];
    const float* Wq = (const float*)d_in[1];
    const float* Wk = (const float*)d_in[2];
    const float* Wv = (const float*)d_in[3];

    unsigned short* ws = (unsigned short*)d_ws;
    unsigned short* Qb = ws;
    unsigned short* Kb = ws + (size_t)N * D;
    unsigned short* Vt = ws + 2 * (size_t)N * D;

    (void)hipFuncSetAttribute((const void*)attn_mfma,
                              hipFuncAttributeMaxDynamicSharedMemorySize, 140288);

    proj_mfma<<<dim3(N / 64, D / 64, 3), 256, 0, stream>>>(X, Wq, Wk, Wv, Qb, Kb, Vt);
    attn_mfma<<<dim3(N / QBLK), 256, 140288, stream>>>(Qb, Kb, Vt, (float*)d_out);
}

// Round 3
// 139.976 us; speedup vs baseline: 350.9762x; 2.3564x over previous
//
#include <hip/hip_runtime.h>
#include <math.h>

#define N 8192
#define D 256
#define QBLK 128
#define KBLK 64

typedef float f32x4 __attribute__((ext_vector_type(4)));
typedef short bf16x8 __attribute__((ext_vector_type(8)));

#define MFMA(a, b, c) __builtin_amdgcn_mfma_f32_16x16x32_bf16((a), (b), (c), 0, 0, 0)

__device__ __forceinline__ unsigned short f2b(float f) {
    unsigned u = __builtin_bit_cast(unsigned, f);
    u = u + 0x7fffu + ((u >> 16) & 1u);            // RNE
    return (unsigned short)(u >> 16);
}
__device__ __forceinline__ unsigned pk2(float a, float b) {
    return (unsigned)f2b(a) | ((unsigned)f2b(b) << 16);
}
__device__ __forceinline__ float b2f(short s) {
    unsigned x = ((unsigned)(unsigned short)s) << 16;
    return __builtin_bit_cast(float, x);
}

// ---------------------------------------------------------------------------
// QKV projection via MFMA (unchanged from round 2 — verified).
// ---------------------------------------------------------------------------
__global__ __launch_bounds__(256) void proj_mfma(
    const float* __restrict__ X, const float* __restrict__ Wq,
    const float* __restrict__ Wk, const float* __restrict__ Wv,
    unsigned short* __restrict__ Qb, unsigned short* __restrict__ Kb,
    unsigned short* __restrict__ Vt)
{
    __shared__ char Wl[32768];
    const int z = blockIdx.z;
    const float* W = (z == 0) ? Wq : (z == 1) ? Wk : Wv;
    const int r0 = blockIdx.x * 64;
    const int c0 = blockIdx.y * 64;
    const int t = threadIdx.x, w = t >> 6, l = t & 63;
    const int lo = l & 15, hi = l >> 4;

    #pragma unroll
    for (int i = 0; i < 16; ++i) {
        int e4 = t + i * 256;
        int col = e4 >> 6, kk4 = e4 & 63;
        float4 f = *(const float4*)&W[(size_t)(c0 + col) * D + kk4 * 4];
        unsigned long long v = (unsigned long long)pk2(f.x, f.y)
                             | ((unsigned long long)pk2(f.z, f.w) << 32);
        *(unsigned long long*)(Wl + col * 512 + ((kk4 * 8) ^ ((col & 7) << 4))) = v;
    }
    __syncthreads();

    bf16x8 xf[8];
    {
        const float* xr = X + (size_t)(r0 + w * 16 + lo) * D;
        #pragma unroll
        for (int ks = 0; ks < 8; ++ks) {
            float4 a = *(const float4*)(xr + ks * 32 + hi * 8);
            float4 b = *(const float4*)(xr + ks * 32 + hi * 8 + 4);
            bf16x8 v;
            v[0] = (short)f2b(a.x); v[1] = (short)f2b(a.y);
            v[2] = (short)f2b(a.z); v[3] = (short)f2b(a.w);
            v[4] = (short)f2b(b.x); v[5] = (short)f2b(b.y);
            v[6] = (short)f2b(b.z); v[7] = (short)f2b(b.w);
            xf[ks] = v;
        }
    }

    f32x4 acc[4];
    #pragma unroll
    for (int nc = 0; nc < 4; ++nc) acc[nc] = (f32x4){0.f, 0.f, 0.f, 0.f};
    #pragma unroll
    for (int ks = 0; ks < 8; ++ks) {
        #pragma unroll
        for (int nc = 0; nc < 4; ++nc) {
            int col = nc * 16 + lo;
            bf16x8 wf = *(const bf16x8*)(Wl + col * 512 +
                                         ((ks * 64 + hi * 16) ^ ((col & 7) << 4)));
            acc[nc] = MFMA(xf[ks], wf, acc[nc]);
        }
    }

    if (z < 2) {
        unsigned short* Y = z ? Kb : Qb;
        #pragma unroll
        for (int nc = 0; nc < 4; ++nc)
            #pragma unroll
            for (int r = 0; r < 4; ++r)
                Y[(size_t)(r0 + w * 16 + hi * 4 + r) * D + c0 + nc * 16 + lo] = f2b(acc[nc][r]);
    } else {
        #pragma unroll
        for (int nc = 0; nc < 4; ++nc) {
            unsigned long long v = (unsigned long long)pk2(acc[nc][0], acc[nc][1])
                                 | ((unsigned long long)pk2(acc[nc][2], acc[nc][3]) << 32);
            *(unsigned long long*)&Vt[(size_t)(c0 + nc * 16 + lo) * N + r0 + w * 16 + hi * 4] = v;
        }
    }
}

// ---------------------------------------------------------------------------
// Flash attention, Qw=32 per wave (2 strips), QBLK=128, K-split across blocks.
// Writes unnormalized O~ (bf16) + per-row (m, l) for the combine kernel.
// LDS: K dbuf 2x32KB @0, Vt dbuf 2x32KB @65536, P 4x4608B @131072 -> 149504 B.
// ---------------------------------------------------------------------------
__device__ __forceinline__ void stage_tile(
    const unsigned short* __restrict__ Kb, const unsigned short* __restrict__ Vt,
    char* kbuf, char* vbuf, int kt, int w, int l)
{
    #pragma unroll
    for (int i = 0; i < 8; ++i) {
        int c = w * 8 + i;
        int dst = c * 64 + l;                      // 16B units
        {
            int key = dst >> 5, xc = dst & 31;
            const unsigned short* gp = Kb + (size_t)(kt + key) * D + (xc ^ (key & 7)) * 8;
            __builtin_amdgcn_global_load_lds(
                (const __attribute__((address_space(1))) void*)gp,
                (__attribute__((address_space(3))) void*)(kbuf + c * 1024), 16, 0, 0);
        }
        {
            int dd = dst >> 3, xc = dst & 7;
            const unsigned short* gp = Vt + (size_t)dd * N + kt + (xc ^ (dd & 7)) * 8;
            __builtin_amdgcn_global_load_lds(
                (const __attribute__((address_space(1))) void*)gp,
                (__attribute__((address_space(3))) void*)(vbuf + c * 1024), 16, 0, 0);
        }
    }
}

template <int KSPLIT>
__global__ __launch_bounds__(256) void attn_mfma(
    const unsigned short* __restrict__ Qb,
    const unsigned short* __restrict__ Kb,
    const unsigned short* __restrict__ Vt,
    unsigned short* __restrict__ Opart,
    float2* __restrict__ ml)
{
    extern __shared__ char smem[];
    const int t = threadIdx.x;
    const int w = t >> 6;
    const int l = t & 63;
    const int lo = l & 15;
    const int hi = l >> 4;
    const int q0 = blockIdx.x * QBLK + w * 32;
    const int split = blockIdx.y;
    const int kbase = split * (N / KSPLIT);
    const int NTS = N / KSPLIT / KBLK;

    char* Pw = smem + 131072 + w * 4608;           // [32 q][72 keys] bf16 (stride 144B)

    // resident Q fragments for both strips
    bf16x8 qf[2][8];
    #pragma unroll
    for (int s = 0; s < 2; ++s) {
        const unsigned short* qrow = Qb + (size_t)(q0 + s * 16 + lo) * D;
        #pragma unroll
        for (int ks = 0; ks < 8; ++ks)
            qf[s][ks] = *(const bf16x8*)(qrow + ks * 32 + hi * 8);
    }

    // prologue: stage tile 0
    stage_tile(Kb, Vt, smem, smem + 65536, kbase, w, l);

    f32x4 Oacc[2][16];
    #pragma unroll
    for (int s = 0; s < 2; ++s)
        #pragma unroll
        for (int i = 0; i < 16; ++i) Oacc[s][i] = (f32x4){0.f, 0.f, 0.f, 0.f};
    float m_run[2] = {-INFINITY, -INFINITY};
    float l_run[2] = {0.f, 0.f};
    const float scale = 0.0625f;                   // 1/sqrt(256)

    __syncthreads();                               // drains vmcnt -> tile 0 ready

    for (int tt = 0; tt < NTS; ++tt) {
        const int cur = tt & 1;
        if (tt + 1 < NTS)
            stage_tile(Kb, Vt, smem + (cur ^ 1) * 32768, smem + 65536 + (cur ^ 1) * 32768,
                       kbase + (tt + 1) * KBLK, w, l);

        const char* Kl = smem + cur * 32768;
        const char* Vl = smem + 65536 + cur * 32768;

        // ---- S^T = K . Q^T for both strips; each K-frag feeds 2 MFMAs
        f32x4 sacc[2][4];
        #pragma unroll
        for (int s = 0; s < 2; ++s)
            #pragma unroll
            for (int kg = 0; kg < 4; ++kg) sacc[s][kg] = (f32x4){0.f, 0.f, 0.f, 0.f};
        #pragma unroll
        for (int ks = 0; ks < 8; ++ks) {
            #pragma unroll
            for (int kg = 0; kg < 4; ++kg) {
                int key = kg * 16 + lo;
                bf16x8 kf = *(const bf16x8*)(Kl + key * 512 +
                                             ((ks * 64 + hi * 16) ^ ((key & 7) << 4)));
                sacc[0][kg] = MFMA(kf, qf[0][ks], sacc[0][kg]);
                sacc[1][kg] = MFMA(kf, qf[1][ks], sacc[1][kg]);
            }
        }

        // ---- online softmax per strip (lane-local 16 vals + shfl 16/32)
        float mx[2];
        #pragma unroll
        for (int s = 0; s < 2; ++s) {
            float m = -INFINITY;
            #pragma unroll
            for (int kg = 0; kg < 4; ++kg)
                #pragma unroll
                for (int r = 0; r < 4; ++r) m = fmaxf(m, sacc[s][kg][r]);
            m *= scale;
            m = fmaxf(m, __shfl_xor(m, 16));
            m = fmaxf(m, __shfl_xor(m, 32));
            mx[s] = m;
        }

        // T13 defer-rescale: only rescale when some row's max grew by >8
        bool need = (mx[0] > m_run[0] + 8.0f) || (mx[1] > m_run[1] + 8.0f);
        if (__any(need)) {
            #pragma unroll
            for (int s = 0; s < 2; ++s) {
                float m_new = fmaxf(m_run[s], mx[s]);
                float corr = __expf(m_run[s] - m_new);
                m_run[s] = m_new;
                l_run[s] *= corr;
                float cr0 = __shfl(corr, hi * 4 + 0);
                float cr1 = __shfl(corr, hi * 4 + 1);
                float cr2 = __shfl(corr, hi * 4 + 2);
                float cr3 = __shfl(corr, hi * 4 + 3);
                #pragma unroll
                for (int nc = 0; nc < 16; ++nc) {
                    Oacc[s][nc][0] *= cr0; Oacc[s][nc][1] *= cr1;
                    Oacc[s][nc][2] *= cr2; Oacc[s][nc][3] *= cr3;
                }
            }
        }

        // ---- P = exp(S - m), row sums
        float p[2][16];
        #pragma unroll
        for (int s = 0; s < 2; ++s) {
            float ts = 0.f;
            #pragma unroll
            for (int kg = 0; kg < 4; ++kg)
                #pragma unroll
                for (int r = 0; r < 4; ++r) {
                    float pv = __expf(sacc[s][kg][r] * scale - m_run[s]);
                    p[s][kg * 4 + r] = pv;
                    ts += pv;
                }
            ts += __shfl_xor(ts, 16);
            ts += __shfl_xor(ts, 32);
            l_run[s] += ts;
        }

        // ---- write P (bf16) to per-wave padded LDS
        #pragma unroll
        for (int s = 0; s < 2; ++s) {
            char* pr = Pw + (s * 16 + lo) * 144;
            #pragma unroll
            for (int kg = 0; kg < 4; ++kg) {
                *(unsigned*)(pr + (kg * 16 + hi * 4) * 2)     = pk2(p[s][kg * 4 + 0], p[s][kg * 4 + 1]);
                *(unsigned*)(pr + (kg * 16 + hi * 4 + 2) * 2) = pk2(p[s][kg * 4 + 2], p[s][kg * 4 + 3]);
            }
        }
        __threadfence_block();

        bf16x8 pa[2][2];
        #pragma unroll
        for (int s = 0; s < 2; ++s) {
            pa[s][0] = *(const bf16x8*)(Pw + (s * 16 + lo) * 144 + hi * 16);
            pa[s][1] = *(const bf16x8*)(Pw + (s * 16 + lo) * 144 + 64 + hi * 16);
        }

        // ---- PV: each V-frag feeds 2 strips
        #pragma unroll
        for (int nc = 0; nc < 16; ++nc) {
            int dd = nc * 16 + lo;
            bf16x8 v0 = *(const bf16x8*)(Vl + dd * 128 + ((hi * 16) ^ ((dd & 7) << 4)));
            bf16x8 v1 = *(const bf16x8*)(Vl + dd * 128 + ((64 + hi * 16) ^ ((dd & 7) << 4)));
            Oacc[0][nc] = MFMA(pa[0][0], v0, Oacc[0][nc]);
            Oacc[0][nc] = MFMA(pa[0][1], v1, Oacc[0][nc]);
            Oacc[1][nc] = MFMA(pa[1][0], v0, Oacc[1][nc]);
            Oacc[1][nc] = MFMA(pa[1][1], v1, Oacc[1][nc]);
        }

        __syncthreads();
    }

    // ---- epilogue: unnormalized O~ (bf16) + (m, l)
    #pragma unroll
    for (int s = 0; s < 2; ++s) {
        const int qrow = q0 + s * 16 + hi * 4;
        #pragma unroll
        for (int nc = 0; nc < 16; ++nc)
            #pragma unroll
            for (int r = 0; r < 4; ++r)
                Opart[((size_t)split * N + qrow + r) * D + nc * 16 + lo] = f2b(Oacc[s][nc][r]);
        if (hi == 0)
            ml[(size_t)split * N + q0 + s * 16 + lo] = make_float2(m_run[s], l_run[s]);
    }
}

// ---------------------------------------------------------------------------
// Combine: O[q][d] = sum_i exp(m_i - M) O~_i[q][d] / sum_i exp(m_i - M) l_i
// ---------------------------------------------------------------------------
__global__ __launch_bounds__(256) void combine_kernel(
    const unsigned short* __restrict__ Opart, const float2* __restrict__ ml,
    float* __restrict__ out, int nsplit)
{
    int idx = blockIdx.x * 256 + threadIdx.x;      // 8-element chunk id
    int q = idx >> 5;
    int d0 = (idx & 31) * 8;

    float M = -INFINITY;
    for (int i = 0; i < nsplit; ++i) M = fmaxf(M, ml[(size_t)i * N + q].x);
    float L = 0.f;
    float acc[8] = {};
    for (int i = 0; i < nsplit; ++i) {
        float2 v = ml[(size_t)i * N + q];
        float wgt = __expf(v.x - M);
        L += wgt * v.y;
        bf16x8 ov = *(const bf16x8*)&Opart[((size_t)i * N + q) * D + d0];
        #pragma unroll
        for (int j = 0; j < 8; ++j) acc[j] += wgt * b2f(ov[j]);
    }
    float r = 1.f / L;
    #pragma unroll
    for (int j = 0; j < 8; ++j) out[(size_t)q * D + d0 + j] = acc[j] * r;
}

extern "C" void kernel_launch(void* const* d_in, const int* in_sizes, int n_in,
                              void* d_out, int out_size, void* d_ws, size_t ws_size,
                              hipStream_t stream) {
    const float* X  = (const float*)d_in[0];
    const float* Wq = (const float*)d_in[1];
    const float* Wk = (const float*)d_in[2];
    const float* Wv = (const float*)d_in[3];

    unsigned short* ws = (unsigned short*)d_ws;
    const size_t ndq = (size_t)N * D;
    unsigned short* Qb = ws;
    unsigned short* Kb = ws + ndq;
    unsigned short* Vt = ws + 2 * ndq;
    unsigned short* Opart = ws + 3 * ndq;

    // KSPLIT=4 needs (3+4)*N*D*2 + 4*N*8 bytes = ~29.7 MB; fall back to 2 if tight
    const size_t need4 = 7 * ndq * 2 + (size_t)4 * N * 8;
    const int ksplit = (ws_size >= need4) ? 4 : 2;
    float2* ml = (float2*)(ws + (3 + ksplit) * ndq);

    (void)hipFuncSetAttribute((const void*)attn_mfma<4>,
                              hipFuncAttributeMaxDynamicSharedMemorySize, 149504);
    (void)hipFuncSetAttribute((const void*)attn_mfma<2>,
                              hipFuncAttributeMaxDynamicSharedMemorySize, 149504);

    proj_mfma<<<dim3(N / 64, D / 64, 3), 256, 0, stream>>>(X, Wq, Wk, Wv, Qb, Kb, Vt);
    if (ksplit == 4)
        attn_mfma<4><<<dim3(N / QBLK, 4), 256, 149504, stream>>>(Qb, Kb, Vt, Opart, ml);
    else
        attn_mfma<2><<<dim3(N / QBLK, 2), 256, 149504, stream>>>(Qb, Kb, Vt, Opart, ml);
    combine_kernel<<<(N * D / 8) / 256, 256, 0, stream>>>(Opart, ml, (float*)d_out, ksplit);
}

// Round 4
// 128.678 us; speedup vs baseline: 381.7925x; 1.0878x over previous
//
#include <hip/hip_runtime.h>
#include <math.h>

#define N 8192
#define D 256
#define QBLK 256          // 8 waves x 32 q-rows
#define KBLK 64

typedef float f32x4 __attribute__((ext_vector_type(4)));
typedef short bf16x8 __attribute__((ext_vector_type(8)));

#define MFMA(a, b, c) __builtin_amdgcn_mfma_f32_16x16x32_bf16((a), (b), (c), 0, 0, 0)

__device__ __forceinline__ unsigned short f2b(float f) {
    unsigned u = __builtin_bit_cast(unsigned, f);
    u = u + 0x7fffu + ((u >> 16) & 1u);            // RNE
    return (unsigned short)(u >> 16);
}
__device__ __forceinline__ unsigned pk2(float a, float b) {
    return (unsigned)f2b(a) | ((unsigned)f2b(b) << 16);
}
__device__ __forceinline__ unsigned cvtpk(float a, float b) {
    unsigned r;
    asm("v_cvt_pk_bf16_f32 %0, %1, %2" : "=v"(r) : "v"(a), "v"(b));
    return r;
}
__device__ __forceinline__ float b2f(short s) {
    unsigned x = ((unsigned)(unsigned short)s) << 16;
    return __builtin_bit_cast(float, x);
}

// ---------------------------------------------------------------------------
// QKV projection via MFMA (unchanged — verified). Q,K row-major bf16; V
// transposed (Vt[d][key]).
// ---------------------------------------------------------------------------
__global__ __launch_bounds__(256) void proj_mfma(
    const float* __restrict__ X, const float* __restrict__ Wq,
    const float* __restrict__ Wk, const float* __restrict__ Wv,
    unsigned short* __restrict__ Qb, unsigned short* __restrict__ Kb,
    unsigned short* __restrict__ Vt)
{
    __shared__ char Wl[32768];
    const int z = blockIdx.z;
    const float* W = (z == 0) ? Wq : (z == 1) ? Wk : Wv;
    const int r0 = blockIdx.x * 64;
    const int c0 = blockIdx.y * 64;
    const int t = threadIdx.x, w = t >> 6, l = t & 63;
    const int lo = l & 15, hi = l >> 4;

    #pragma unroll
    for (int i = 0; i < 16; ++i) {
        int e4 = t + i * 256;
        int col = e4 >> 6, kk4 = e4 & 63;
        float4 f = *(const float4*)&W[(size_t)(c0 + col) * D + kk4 * 4];
        unsigned long long v = (unsigned long long)pk2(f.x, f.y)
                             | ((unsigned long long)pk2(f.z, f.w) << 32);
        *(unsigned long long*)(Wl + col * 512 + ((kk4 * 8) ^ ((col & 7) << 4))) = v;
    }
    __syncthreads();

    bf16x8 xf[8];
    {
        const float* xr = X + (size_t)(r0 + w * 16 + lo) * D;
        #pragma unroll
        for (int ks = 0; ks < 8; ++ks) {
            float4 a = *(const float4*)(xr + ks * 32 + hi * 8);
            float4 b = *(const float4*)(xr + ks * 32 + hi * 8 + 4);
            bf16x8 v;
            v[0] = (short)f2b(a.x); v[1] = (short)f2b(a.y);
            v[2] = (short)f2b(a.z); v[3] = (short)f2b(a.w);
            v[4] = (short)f2b(b.x); v[5] = (short)f2b(b.y);
            v[6] = (short)f2b(b.z); v[7] = (short)f2b(b.w);
            xf[ks] = v;
        }
    }

    f32x4 acc[4];
    #pragma unroll
    for (int nc = 0; nc < 4; ++nc) acc[nc] = (f32x4){0.f, 0.f, 0.f, 0.f};
    #pragma unroll
    for (int ks = 0; ks < 8; ++ks) {
        #pragma unroll
        for (int nc = 0; nc < 4; ++nc) {
            int col = nc * 16 + lo;
            bf16x8 wf = *(const bf16x8*)(Wl + col * 512 +
                                         ((ks * 64 + hi * 16) ^ ((col & 7) << 4)));
            acc[nc] = MFMA(xf[ks], wf, acc[nc]);
        }
    }

    if (z < 2) {
        unsigned short* Y = z ? Kb : Qb;
        #pragma unroll
        for (int nc = 0; nc < 4; ++nc)
            #pragma unroll
            for (int r = 0; r < 4; ++r)
                Y[(size_t)(r0 + w * 16 + hi * 4 + r) * D + c0 + nc * 16 + lo] = f2b(acc[nc][r]);
    } else {
        #pragma unroll
        for (int nc = 0; nc < 4; ++nc) {
            unsigned long long v = (unsigned long long)pk2(acc[nc][0], acc[nc][1])
                                 | ((unsigned long long)pk2(acc[nc][2], acc[nc][3]) << 32);
            *(unsigned long long*)&Vt[(size_t)(c0 + nc * 16 + lo) * N + r0 + w * 16 + hi * 4] = v;
        }
    }
}

// ---------------------------------------------------------------------------
// Staging for 512-thread blocks. K rows staged in PERMUTED order pi(row) so
// that the QK^T output lane-ownership matches the PV A-fragment layout
// (P never touches LDS). pi = bit-shuffle: {b5, b3b2, b4, b1b0}.
// ---------------------------------------------------------------------------
__device__ __forceinline__ void stage_tile8(
    const unsigned short* __restrict__ Kb, const unsigned short* __restrict__ Vt,
    char* kbuf, char* vbuf, int kt, int t)
{
    #pragma unroll
    for (int i = 0; i < 4; ++i) {
        int c = t + i * 512;                       // 16B chunk id, 0..2047
        {
            int row = c >> 5, xc = c & 31;         // K: 64 rows x 32 chunks
            int pk = ((row >> 5) << 5) | (((row >> 2) & 3) << 3)
                   | (((row >> 4) & 1) << 2) | (row & 3);
            const unsigned short* gp = Kb + (size_t)(kt + pk) * D + (xc ^ (row & 7)) * 8;
            __builtin_amdgcn_global_load_lds(
                (const __attribute__((address_space(1))) void*)gp,
                (__attribute__((address_space(3))) void*)(kbuf + c * 16), 16, 0, 0);
        }
        {
            int dd = c >> 3, xc = c & 7;           // V: 256 rows x 8 chunks
            const unsigned short* gp = Vt + (size_t)dd * N + kt + (xc ^ (dd & 7)) * 8;
            __builtin_amdgcn_global_load_lds(
                (const __attribute__((address_space(1))) void*)gp,
                (__attribute__((address_space(3))) void*)(vbuf + c * 16), 16, 0, 0);
        }
    }
}

// ---------------------------------------------------------------------------
// Flash attention: 8 waves x 32 q-rows, KBLK=64, K-split across blocks.
// In-register P via permuted K staging. LDS: K dbuf 2x32K @0, V dbuf 2x32K
// @65536 -> 131072 B.
// ---------------------------------------------------------------------------
template <int KSPLIT>
__global__ __launch_bounds__(512, 2) void attn_mfma(
    const unsigned short* __restrict__ Qb,
    const unsigned short* __restrict__ Kb,
    const unsigned short* __restrict__ Vt,
    unsigned short* __restrict__ Opart,
    float2* __restrict__ ml)
{
    extern __shared__ char smem[];
    const int t = threadIdx.x;
    const int w = t >> 6;
    const int l = t & 63;
    const int lo = l & 15;
    const int hi = l >> 4;
    const int q0 = blockIdx.x * QBLK + w * 32;
    const int split = blockIdx.y;
    const int kbase = split * (N / KSPLIT);
    const int NTS = N / KSPLIT / KBLK;

    bf16x8 qf[2][8];
    #pragma unroll
    for (int s = 0; s < 2; ++s) {
        const unsigned short* qrow = Qb + (size_t)(q0 + s * 16 + lo) * D;
        #pragma unroll
        for (int ks = 0; ks < 8; ++ks)
            qf[s][ks] = *(const bf16x8*)(qrow + ks * 32 + hi * 8);
    }

    stage_tile8(Kb, Vt, smem, smem + 65536, kbase, t);

    f32x4 Oacc[2][16];
    #pragma unroll
    for (int s = 0; s < 2; ++s)
        #pragma unroll
        for (int i = 0; i < 16; ++i) Oacc[s][i] = (f32x4){0.f, 0.f, 0.f, 0.f};
    float m_run[2] = {-INFINITY, -INFINITY};
    float l_run[2] = {0.f, 0.f};
    const float scale = 0.0625f;                   // 1/sqrt(256)

    __syncthreads();                               // tile 0 ready

    for (int tt = 0; tt < NTS; ++tt) {
        const int cur = tt & 1;
        if (tt + 1 < NTS)
            stage_tile8(Kb, Vt, smem + (cur ^ 1) * 32768,
                        smem + 65536 + (cur ^ 1) * 32768,
                        kbase + (tt + 1) * KBLK, t);

        const char* Kl = smem + cur * 32768;
        const char* Vl = smem + 65536 + cur * 32768;

        // ---- S^T = K . Q^T (LDS row space; phys keys permuted by pi)
        f32x4 sacc[2][4];
        #pragma unroll
        for (int s = 0; s < 2; ++s)
            #pragma unroll
            for (int kg = 0; kg < 4; ++kg) sacc[s][kg] = (f32x4){0.f, 0.f, 0.f, 0.f};
        __builtin_amdgcn_s_setprio(1);
        #pragma unroll
        for (int ks = 0; ks < 8; ++ks) {
            #pragma unroll
            for (int kg = 0; kg < 4; ++kg) {
                int key = kg * 16 + lo;
                bf16x8 kf = *(const bf16x8*)(Kl + key * 512 +
                                             ((ks * 64 + hi * 16) ^ ((key & 7) << 4)));
                sacc[0][kg] = MFMA(kf, qf[0][ks], sacc[0][kg]);
                sacc[1][kg] = MFMA(kf, qf[1][ks], sacc[1][kg]);
            }
        }
        __builtin_amdgcn_s_setprio(0);

        // ---- online softmax (lane-local 16 vals + shfl 16/32)
        float mx[2];
        #pragma unroll
        for (int s = 0; s < 2; ++s) {
            float m = -INFINITY;
            #pragma unroll
            for (int kg = 0; kg < 4; ++kg)
                #pragma unroll
                for (int r = 0; r < 4; ++r) m = fmaxf(m, sacc[s][kg][r]);
            m *= scale;
            m = fmaxf(m, __shfl_xor(m, 16));
            m = fmaxf(m, __shfl_xor(m, 32));
            mx[s] = m;
        }

        bool need = (mx[0] > m_run[0] + 8.0f) || (mx[1] > m_run[1] + 8.0f);
        if (__any(need)) {
            #pragma unroll
            for (int s = 0; s < 2; ++s) {
                float m_new = fmaxf(m_run[s], mx[s]);
                float corr = __expf(m_run[s] - m_new);
                m_run[s] = m_new;
                l_run[s] *= corr;
                float cr0 = __shfl(corr, hi * 4 + 0);
                float cr1 = __shfl(corr, hi * 4 + 1);
                float cr2 = __shfl(corr, hi * 4 + 2);
                float cr3 = __shfl(corr, hi * 4 + 3);
                #pragma unroll
                for (int nc = 0; nc < 16; ++nc) {
                    Oacc[s][nc][0] *= cr0; Oacc[s][nc][1] *= cr1;
                    Oacc[s][nc][2] *= cr2; Oacc[s][nc][3] *= cr3;
                }
            }
        }

        // ---- P = exp(S - m); pack pa in-register (key order matches V)
        bf16x8 pa[2][2];
        #pragma unroll
        for (int s = 0; s < 2; ++s) {
            float p[16];
            float ts = 0.f;
            #pragma unroll
            for (int kg = 0; kg < 4; ++kg)
                #pragma unroll
                for (int r = 0; r < 4; ++r) {
                    float pv = __expf(sacc[s][kg][r] * scale - m_run[s]);
                    p[kg * 4 + r] = pv;
                    ts += pv;
                }
            ts += __shfl_xor(ts, 16);
            ts += __shfl_xor(ts, 32);
            l_run[s] += ts;

            union { unsigned u[4]; bf16x8 v; } u0, u1;
            #pragma unroll
            for (int j = 0; j < 4; ++j) {
                u0.u[j] = cvtpk(p[j * 2], p[j * 2 + 1]);
                u1.u[j] = cvtpk(p[8 + j * 2], p[8 + j * 2 + 1]);
            }
            pa[s][0] = u0.v;
            pa[s][1] = u1.v;
        }

        // ---- PV
        __builtin_amdgcn_s_setprio(1);
        #pragma unroll
        for (int nc = 0; nc < 16; ++nc) {
            int dd = nc * 16 + lo;
            bf16x8 v0 = *(const bf16x8*)(Vl + dd * 128 + ((hi * 16) ^ ((dd & 7) << 4)));
            bf16x8 v1 = *(const bf16x8*)(Vl + dd * 128 + ((64 + hi * 16) ^ ((dd & 7) << 4)));
            Oacc[0][nc] = MFMA(pa[0][0], v0, Oacc[0][nc]);
            Oacc[0][nc] = MFMA(pa[0][1], v1, Oacc[0][nc]);
            Oacc[1][nc] = MFMA(pa[1][0], v0, Oacc[1][nc]);
            Oacc[1][nc] = MFMA(pa[1][1], v1, Oacc[1][nc]);
        }
        __builtin_amdgcn_s_setprio(0);

        __syncthreads();                           // next tile landed; cur free
    }

    // ---- epilogue: unnormalized O~ (bf16) + (m, l)
    #pragma unroll
    for (int s = 0; s < 2; ++s) {
        const int qrow = q0 + s * 16 + hi * 4;
        #pragma unroll
        for (int nc = 0; nc < 16; ++nc)
            #pragma unroll
            for (int r = 0; r < 4; ++r)
                Opart[((size_t)split * N + qrow + r) * D + nc * 16 + lo] = f2b(Oacc[s][nc][r]);
        if (hi == 0)
            ml[(size_t)split * N + q0 + s * 16 + lo] = make_float2(m_run[s], l_run[s]);
    }
}

// ---------------------------------------------------------------------------
// Combine: O[q][d] = sum_i exp(m_i - M) O~_i[q][d] / sum_i exp(m_i - M) l_i
// ---------------------------------------------------------------------------
__global__ __launch_bounds__(256) void combine_kernel(
    const unsigned short* __restrict__ Opart, const float2* __restrict__ ml,
    float* __restrict__ out, int nsplit)
{
    int idx = blockIdx.x * 256 + threadIdx.x;
    int q = idx >> 5;
    int d0 = (idx & 31) * 8;

    float M = -INFINITY;
    for (int i = 0; i < nsplit; ++i) M = fmaxf(M, ml[(size_t)i * N + q].x);
    float L = 0.f;
    float acc[8] = {};
    for (int i = 0; i < nsplit; ++i) {
        float2 v = ml[(size_t)i * N + q];
        float wgt = __expf(v.x - M);
        L += wgt * v.y;
        bf16x8 ov = *(const bf16x8*)&Opart[((size_t)i * N + q) * D + d0];
        #pragma unroll
        for (int j = 0; j < 8; ++j) acc[j] += wgt * b2f(ov[j]);
    }
    float r = 1.f / L;
    #pragma unroll
    for (int j = 0; j < 8; ++j) out[(size_t)q * D + d0 + j] = acc[j] * r;
}

extern "C" void kernel_launch(void* const* d_in, const int* in_sizes, int n_in,
                              void* d_out, int out_size, void* d_ws, size_t ws_size,
                              hipStream_t stream) {
    const float* X  = (const float*)d_in[0];
    const float* Wq = (const float*)d_in[1];
    const float* Wk = (const float*)d_in[2];
    const float* Wv = (const float*)d_in[3];

    unsigned short* ws = (unsigned short*)d_ws;
    const size_t ndq = (size_t)N * D;
    unsigned short* Qb = ws;
    unsigned short* Kb = ws + ndq;
    unsigned short* Vt = ws + 2 * ndq;
    unsigned short* Opart = ws + 3 * ndq;

    auto need = [ndq](int ks) {
        return (size_t)(3 + ks) * ndq * 2 + (size_t)ks * N * 8;
    };
    const int ksplit = (ws_size >= need(8)) ? 8 : (ws_size >= need(4)) ? 4 : 2;
    float2* ml = (float2*)(ws + (3 + ksplit) * ndq);

    (void)hipFuncSetAttribute((const void*)attn_mfma<8>,
                              hipFuncAttributeMaxDynamicSharedMemorySize, 131072);
    (void)hipFuncSetAttribute((const void*)attn_mfma<4>,
                              hipFuncAttributeMaxDynamicSharedMemorySize, 131072);
    (void)hipFuncSetAttribute((const void*)attn_mfma<2>,
                              hipFuncAttributeMaxDynamicSharedMemorySize, 131072);

    proj_mfma<<<dim3(N / 64, D / 64, 3), 256, 0, stream>>>(X, Wq, Wk, Wv, Qb, Kb, Vt);
    if (ksplit == 8)
        attn_mfma<8><<<dim3(N / QBLK, 8), 512, 131072, stream>>>(Qb, Kb, Vt, Opart, ml);
    else if (ksplit == 4)
        attn_mfma<4><<<dim3(N / QBLK, 4), 512, 131072, stream>>>(Qb, Kb, Vt, Opart, ml);
    else
        attn_mfma<2><<<dim3(N / QBLK, 2), 512, 131072, stream>>>(Qb, Kb, Vt, Opart, ml);
    combine_kernel<<<(N * D / 8) / 256, 256, 0, stream>>>(Opart, ml, (float*)d_out, ksplit);
}